// Round 1
// baseline (421.912 us; speedup 1.0000x reference)
//
#include <hip/hip_runtime.h>
#include <hip/hip_bf16.h>
#include <cmath>
#include <cstdint>

// R0: bf16 MFMA GEMM (m97 structure: 128x128 tile, BK=64, global_load_lds x16)
// + separate ternary-quantize passes into d_ws.
// Numerics: x_q in {-0.5,0,0.5} exact in bf16; w_rram ~ N(0,0.05), bf16 RNE
// rounding error accumulates to ~1e-3 << 0.105 threshold.
// Double-precision threshold compares to match numpy float64 semantics at
// x == 0.33f (P(hit) ~ 0.36 over 33.5M samples).

#define AS1 __attribute__((address_space(1)))
#define AS3 __attribute__((address_space(3)))

typedef unsigned short u16;
typedef __bf16 bf16x8 __attribute__((ext_vector_type(8)));
typedef float f32x4 __attribute__((ext_vector_type(4)));
typedef unsigned short u16x4 __attribute__((ext_vector_type(4)));

#define BM 128
#define BN 128
#define BK 64

__device__ __forceinline__ u16 f2bf_rne(float f) {
  uint32_t u = __float_as_uint(f);
  u += 0x7FFFu + ((u >> 16) & 1u);
  return (u16)(u >> 16);
}

// activation ternary -> bf16 bits of {-0.5, 0, +0.5}
__device__ __forceinline__ u16 ter_x(float v) {
  double d = (double)v;
  return d > 0.33 ? (u16)0x3F00u : (d < -0.33 ? (u16)0xBF00u : (u16)0u);
}

// weight ternary -> fp32 {-0.6, 0, +0.6}
__device__ __forceinline__ float ter_w(float v) {
  double d = (double)v;
  return d > 0.2 ? 0.6f : (d < -0.2 ? -0.6f : 0.0f);
}

__global__ void quant_x_kernel(const float* __restrict__ x, u16* __restrict__ xq,
                               long n4) {
  long i = (long)blockIdx.x * blockDim.x + threadIdx.x;
  if (i >= n4) return;
  float4 v = ((const float4*)x)[i];
  u16x4 q;
  q.x = ter_x(v.x); q.y = ter_x(v.y); q.z = ter_x(v.z); q.w = ter_x(v.w);
  ((u16x4*)xq)[i] = q;
}

__global__ void quant_w_kernel(const float* __restrict__ w,
                               const float* __restrict__ rr,
                               u16* __restrict__ wq, long n4) {
  long i = (long)blockIdx.x * blockDim.x + threadIdx.x;
  if (i >= n4) return;
  float4 a = ((const float4*)w)[i];
  float4 b = ((const float4*)rr)[i];
  u16x4 q;
  q.x = f2bf_rne(ter_w(a.x) + b.x);
  q.y = f2bf_rne(ter_w(a.y) + b.y);
  q.z = f2bf_rne(ter_w(a.z) + b.z);
  q.w = f2bf_rne(ter_w(a.w) + b.w);
  ((u16x4*)wq)[i] = q;
}

// async 16B/lane global->LDS; LDS dest is wave-uniform base + lane*16
__device__ __forceinline__ void gld_lds16(const void* g, void* l) {
  __builtin_amdgcn_global_load_lds((AS1 void*)g, (AS3 void*)l, 16, 0, 0);
}

// C[m][n] = sum_k A[m][k] * B[n][k]   (both K-contiguous bf16; C fp32)
// FUSED: A comes from fp32 x quantized during staging (ws too small fallback).
template <bool FUSED>
__global__ __launch_bounds__(256) void gemm_bt_kernel(
    const u16* __restrict__ Aq, const float* __restrict__ Xf,
    const u16* __restrict__ Bq, float* __restrict__ C,
    int M, int N, int K) {
  __shared__ u16 As[BM * BK];
  __shared__ u16 Bs[BN * BK];

  const int tid  = threadIdx.x;
  const int wid  = tid >> 6;
  const int lane = tid & 63;

  const int m0 = blockIdx.y * BM;
  const int n0 = blockIdx.x * BN;

  // staging decomposition: 1 inst = 64 lanes x 16B = 8 rows of 128B (BK=64 bf16)
  const int r8 = lane >> 3;        // row within 8-row group
  const int c8 = (lane & 7) * 8;   // ushort offset within row

  // wave -> 64x64 quadrant; 4x4 grid of 16x16 MFMA tiles
  const int mw = (wid >> 1) * 64;
  const int nw = (wid & 1) * 64;
  const int fr = lane & 15;        // fragment row index (m or n)
  const int fk = (lane >> 4) * 8;  // fragment k offset

  f32x4 acc[4][4] = {};

  for (int k0 = 0; k0 < K; k0 += BK) {
    // stage B tile (always async, bf16 in ws)
#pragma unroll
    for (int t = 0; t < 4; ++t) {
      const int rbase = wid * 32 + t * 8;
      gld_lds16(Bq + (size_t)(n0 + rbase + r8) * K + k0 + c8, &Bs[rbase * BK]);
    }
    if constexpr (!FUSED) {
#pragma unroll
      for (int t = 0; t < 4; ++t) {
        const int rbase = wid * 32 + t * 8;
        gld_lds16(Aq + (size_t)(m0 + rbase + r8) * K + k0 + c8, &As[rbase * BK]);
      }
    } else {
      // quantize-on-stage: 128x64 fp32 tile -> bf16 LDS
#pragma unroll
      for (int it = 0; it < 8; ++it) {
        const int idx = it * 256 + tid;  // 0..2047 float4 slots
        const int row = idx >> 4;        // 16 float4 per 64-float row
        const int c4  = (idx & 15) * 4;
        const float4 v = *(const float4*)&Xf[(size_t)(m0 + row) * K + k0 + c4];
        u16x4 q;
        q.x = ter_x(v.x); q.y = ter_x(v.y); q.z = ter_x(v.z); q.w = ter_x(v.w);
        *(u16x4*)&As[row * BK + c4] = q;
      }
    }
    __syncthreads();

#pragma unroll
    for (int kk = 0; kk < BK; kk += 32) {
      bf16x8 a[4], b[4];
#pragma unroll
      for (int i = 0; i < 4; ++i)
        a[i] = *(const bf16x8*)&As[(mw + i * 16 + fr) * BK + kk + fk];
#pragma unroll
      for (int j = 0; j < 4; ++j)
        b[j] = *(const bf16x8*)&Bs[(nw + j * 16 + fr) * BK + kk + fk];
#pragma unroll
      for (int i = 0; i < 4; ++i)
#pragma unroll
        for (int j = 0; j < 4; ++j)
          acc[i][j] =
              __builtin_amdgcn_mfma_f32_16x16x32_bf16(a[i], b[j], acc[i][j], 0, 0, 0);
    }
    __syncthreads();
  }

  // C/D layout: row = (lane>>4)*4 + reg, col = lane&15  [measured m89/m91]
  const int om = m0 + mw + (lane >> 4) * 4;
  const int on = n0 + nw + (lane & 15);
#pragma unroll
  for (int i = 0; i < 4; ++i)
#pragma unroll
    for (int j = 0; j < 4; ++j)
#pragma unroll
      for (int r = 0; r < 4; ++r)
        C[(size_t)(om + i * 16 + r) * N + (on + j * 16)] = acc[i][j][r];
}

extern "C" void kernel_launch(void* const* d_in, const int* in_sizes, int n_in,
                              void* d_out, int out_size, void* d_ws, size_t ws_size,
                              hipStream_t stream) {
  const float* x  = (const float*)d_in[0];
  const float* w  = (const float*)d_in[1];
  const float* rr = (const float*)d_in[2];
  float* out = (float*)d_out;

  const long xn = (long)in_sizes[0];
  const long wn = (long)in_sizes[1];
  const int K = (int)llround(std::sqrt((double)wn));  // weight is [D,D]
  const int N = K;
  const int M = (int)(xn / K);

  u16* wq = (u16*)d_ws;
  u16* xq = (u16*)d_ws + (size_t)N * K;
  const size_t need = ((size_t)M * K + (size_t)N * K) * sizeof(u16);

  {
    long n4 = wn / 4;
    quant_w_kernel<<<(int)((n4 + 255) / 256), 256, 0, stream>>>(w, rr, wq, n4);
  }

  dim3 grid(N / BN, M / BM);
  if (ws_size >= need) {
    long n4 = xn / 4;
    quant_x_kernel<<<(int)((n4 + 255) / 256), 256, 0, stream>>>(x, xq, n4);
    gemm_bt_kernel<false><<<grid, 256, 0, stream>>>(xq, nullptr, wq, out, M, N, K);
  } else {
    gemm_bt_kernel<true><<<grid, 256, 0, stream>>>(nullptr, x, wq, out, M, N, K);
  }
}